// Round 1
// baseline (405.779 us; speedup 1.0000x reference)
//
#include <hip/hip_runtime.h>
#include <math.h>

#define NA 5
#define HH 76
#define WW 76
#define HWSZ (HH * WW)          // 5776
#define HW4 (HWSZ / 4)          // 1444
#define OBJECT_SCALE 5.0f
#define SIL_THRESH 0.6f

// ws layout (floats): [0..5) accumulators (sx,sy,sw,sh,sconf); [16 + b*12 ...) per-batch records
// record: 0:gx 1:gy 2:gw 3:gh 4:tx 5:ty 6:tw 7:th 8:best(int) 9:gi(int) 10:gj(int) 11:pad
#define REC_OFF 16
#define REC_STRIDE 12

__constant__ float ANC_W[NA] = {0.57273f, 1.87446f, 3.33843f, 7.88282f, 9.77052f};
__constant__ float ANC_H[NA] = {0.677385f, 2.06253f, 5.47434f, 3.52778f, 9.16828f};

__global__ void prep_kernel(const float* __restrict__ target, float* __restrict__ ws, int bs) {
    int b = threadIdx.x;
    if (b < 5) ws[b] = 0.0f;                 // zero accumulators (ws is poisoned each call)
    if (b >= bs) return;
    float gx = target[b * 4 + 0] * (float)WW;
    float gy = target[b * 4 + 1] * (float)HH;
    float gw = target[b * 4 + 2] * (float)WW;
    float gh = target[b * 4 + 3] * (float)HH;
    // best anchor: IoU of (0,0,gw,gh) vs (0,0,aw,ah) reduces to aligned-box IoU
    int best = 0;
    float bestv = -1.0f;
#pragma unroll
    for (int a = 0; a < NA; ++a) {
        float aw = ANC_W[a], ah = ANC_H[a];
        float inter = fminf(gw, aw) * fminf(gh, ah);
        float uni = gw * gh + aw * ah - inter;
        float iou = inter / uni;
        if (iou > bestv) { bestv = iou; best = a; }   // first-max wins ties (matches argmax)
    }
    int gi = (int)gx;
    int gj = (int)gy;
    float* r = ws + REC_OFF + b * REC_STRIDE;
    r[0] = gx; r[1] = gy; r[2] = gw; r[3] = gh;
    r[4] = gx - (float)gi;
    r[5] = gy - (float)gj;
    r[6] = logf(gw / ANC_W[best]);
    r[7] = logf(gh / ANC_H[best]);
    ((int*)r)[8] = best;
    ((int*)r)[9] = gi;
    ((int*)r)[10] = gj;
}

__device__ __forceinline__ float sigmoidf_fast(float x) {
    return 1.0f / (1.0f + __expf(-x));
}

__global__ __launch_bounds__(256) void
region_loss_main(const float* __restrict__ pred, float* __restrict__ ws, int bs) {
    const int G = bs * NA * HW4;   // float4-groups; 76 % 4 == 0 so each group stays in one row
    float ax = 0.f, ay = 0.f, aw_ = 0.f, ah_ = 0.f, ac = 0.f;

    for (int g = blockIdx.x * blockDim.x + threadIdx.x; g < G; g += gridDim.x * blockDim.x) {
        int ba = g / HW4;          // b * NA + a
        int r  = g - ba * HW4;
        int b  = ba / NA;
        int a  = ba - b * NA;
        int e0 = r * 4;
        int j  = e0 / WW;
        int i0 = e0 - j * WW;

        const float* base = pred + (size_t)ba * 5 * HWSZ + e0;
        float4 px = *(const float4*)(base);
        float4 py = *(const float4*)(base + HWSZ);
        float4 pw = *(const float4*)(base + 2 * HWSZ);
        float4 ph = *(const float4*)(base + 3 * HWSZ);
        float4 pc = *(const float4*)(base + 4 * HWSZ);
        float vx[4] = {px.x, px.y, px.z, px.w};
        float vy[4] = {py.x, py.y, py.z, py.w};
        float vw[4] = {pw.x, pw.y, pw.z, pw.w};
        float vh[4] = {ph.x, ph.y, ph.z, ph.w};
        float vc[4] = {pc.x, pc.y, pc.z, pc.w};

        const float* rec = ws + REC_OFF + b * REC_STRIDE;
        float gx = rec[0], gy = rec[1], gw = rec[2], gh = rec[3];
        int best = ((const int*)rec)[8];
        int gi   = ((const int*)rec)[9];
        int gj   = ((const int*)rec)[10];
        float anw = ANC_W[a], anh = ANC_H[a];
        bool rowhit = (a == best) && (j == gj) && (gi >= i0) && (gi < i0 + 4);

#pragma unroll
        for (int k = 0; k < 4; ++k) {
            float sx = sigmoidf_fast(vx[k]);
            float sy = sigmoidf_fast(vy[k]);
            float sc = sigmoidf_fast(vc[k]);
            float bw = __expf(vw[k]) * anw;
            float bh = __expf(vh[k]) * anh;
            float bx = sx + (float)(i0 + k);
            float by = sy + (float)j;
            // IoU(gt, pred-box)
            float mx = fminf(gx - gw * 0.5f, bx - bw * 0.5f);
            float Mx = fmaxf(gx + gw * 0.5f, bx + bw * 0.5f);
            float my = fminf(gy - gh * 0.5f, by - bh * 0.5f);
            float My = fmaxf(gy + gh * 0.5f, by + bh * 0.5f);
            float cw = gw + bw - (Mx - mx);
            float ch = gh + bh - (My - my);
            float carea = (cw <= 0.f || ch <= 0.f) ? 0.f : cw * ch;
            float uarea = gw * gh + bw * bh - carea;
            float iou = carea / uarea;

            float cmask = (iou > SIL_THRESH) ? 0.f : 1.f;
            float tx = 0.5f, ty = 0.5f, tw = 0.f, th = 0.f, tconf = 0.f;
            if (rowhit && (i0 + k) == gi) {
                cmask = OBJECT_SCALE;
                tx = rec[4]; ty = rec[5]; tw = rec[6]; th = rec[7];
                tconf = iou;   // iou_t == iou_all at the responsible cell
            }
            float dx = sx - tx, dy = sy - ty;
            float dw = vw[k] - tw, dh = vh[k] - th;
            float dc = sc - tconf;
            ax += dx * dx;
            ay += dy * dy;
            aw_ += dw * dw;
            ah_ += dh * dh;
            ac += cmask * dc * dc;
        }
    }

    // block reduction: wave shuffle -> LDS -> 5 atomics per block
    __shared__ float sred[4][5];
    int lane = threadIdx.x & 63;
    int wid  = threadIdx.x >> 6;
    float vals[5] = {ax, ay, aw_, ah_, ac};
#pragma unroll
    for (int v = 0; v < 5; ++v) {
        float x = vals[v];
#pragma unroll
        for (int off = 32; off > 0; off >>= 1) x += __shfl_down(x, off, 64);
        if (lane == 0) sred[wid][v] = x;
    }
    __syncthreads();
    if (threadIdx.x < 5) {
        float s = sred[0][threadIdx.x] + sred[1][threadIdx.x] +
                  sred[2][threadIdx.x] + sred[3][threadIdx.x];
        atomicAdd(&ws[threadIdx.x], s);
    }
}

__global__ void finish_kernel(const float* __restrict__ ws, float* __restrict__ out) {
    float lx = ws[0] * 0.5f;
    float ly = ws[1] * 0.5f;
    float lw = ws[2] * 0.5f;
    float lh = ws[3] * 0.5f;
    float lc = ws[4] * 0.5f;
    out[0] = lx + ly + lw + lh + lc;
    out[1] = lx;
    out[2] = ly;
    out[3] = lw;
    out[4] = lh;
    out[5] = lc;
}

extern "C" void kernel_launch(void* const* d_in, const int* in_sizes, int n_in,
                              void* d_out, int out_size, void* d_ws, size_t ws_size,
                              hipStream_t stream) {
    const float* pred   = (const float*)d_in[0];
    const float* target = (const float*)d_in[1];
    float* ws  = (float*)d_ws;
    float* out = (float*)d_out;
    int bs = in_sizes[1] / 4;   // 512

    prep_kernel<<<1, 512, 0, stream>>>(target, ws, bs);
    region_loss_main<<<2560, 256, 0, stream>>>(pred, ws, bs);
    finish_kernel<<<1, 1, 0, stream>>>(ws, out);
}

// Round 2
// 383.446 us; speedup vs baseline: 1.0582x; 1.0582x over previous
//
#include <hip/hip_runtime.h>
#include <math.h>

#define NA 5
#define HH 76
#define WW 76
#define HWSZ (HH * WW)          // 5776
#define HW4 (HWSZ / 4)          // 1444
#define OBJECT_SCALE 5.0f
#define SIL_THRESH 0.6f

// ws layout (floats): [0..5) accumulators (sx,sy,sw,sh,sconf); [16 + b*12 ...) per-batch records
// record: 0:gx 1:gy 2:gw 3:gh 4:tx 5:ty 6:tw 7:th 8:best(int) 9:gi(int) 10:gj(int) 11:pad
#define REC_OFF 16
#define REC_STRIDE 12

__constant__ float ANC_W[NA] = {0.57273f, 1.87446f, 3.33843f, 7.88282f, 9.77052f};
__constant__ float ANC_H[NA] = {0.677385f, 2.06253f, 5.47434f, 3.52778f, 9.16828f};

typedef float v4f __attribute__((ext_vector_type(4)));

__global__ void prep_kernel(const float* __restrict__ target, float* __restrict__ ws, int bs) {
    int b = threadIdx.x;
    if (b < 5) ws[b] = 0.0f;                 // zero accumulators (ws is poisoned each call)
    if (b >= bs) return;
    float gx = target[b * 4 + 0] * (float)WW;
    float gy = target[b * 4 + 1] * (float)HH;
    float gw = target[b * 4 + 2] * (float)WW;
    float gh = target[b * 4 + 3] * (float)HH;
    // best anchor: IoU of (0,0,gw,gh) vs (0,0,aw,ah) reduces to aligned-box IoU
    int best = 0;
    float bestv = -1.0f;
#pragma unroll
    for (int a = 0; a < NA; ++a) {
        float aw = ANC_W[a], ah = ANC_H[a];
        float inter = fminf(gw, aw) * fminf(gh, ah);
        float uni = gw * gh + aw * ah - inter;
        float iou = inter / uni;
        if (iou > bestv) { bestv = iou; best = a; }   // first-max wins ties (matches argmax)
    }
    int gi = (int)gx;
    int gj = (int)gy;
    float* r = ws + REC_OFF + b * REC_STRIDE;
    r[0] = gx; r[1] = gy; r[2] = gw; r[3] = gh;
    r[4] = gx - (float)gi;
    r[5] = gy - (float)gj;
    r[6] = logf(gw / ANC_W[best]);
    r[7] = logf(gh / ANC_H[best]);
    ((int*)r)[8] = best;
    ((int*)r)[9] = gi;
    ((int*)r)[10] = gj;
}

__device__ __forceinline__ float sigmoidf_fast(float x) {
    return 1.0f / (1.0f + __expf(-x));
}

// One block per (b, a) plane: grid.x == bs * NA == 2560.
__global__ __launch_bounds__(256) void
region_loss_main(const float* __restrict__ pred, float* __restrict__ ws) {
    const int ba = blockIdx.x;
    const int b  = ba / NA;
    const int a  = ba - b * NA;

    // per-batch record: uniform per block, cached
    const float* rec = ws + REC_OFF + b * REC_STRIDE;
    const float gx = rec[0], gy = rec[1], gw = rec[2], gh = rec[3];
    const float tx_s = rec[4], ty_s = rec[5], tw_s = rec[6], th_s = rec[7];
    const int best = ((const int*)rec)[8];
    const int gi   = ((const int*)rec)[9];
    const int gj   = ((const int*)rec)[10];
    const float anw = ANC_W[a], anh = ANC_H[a];
    const bool anchit = (a == best);
    const float gxm = gx - gw * 0.5f, gxM = gx + gw * 0.5f;
    const float gym = gy - gh * 0.5f, gyM = gy + gh * 0.5f;
    const float garea = gw * gh;

    const float* base = pred + (size_t)ba * 5 * HWSZ;
    float ax = 0.f, ay = 0.f, aw_ = 0.f, ah_ = 0.f, ac = 0.f;

    for (int r = threadIdx.x; r < HW4; r += 256) {
        const int e0 = r * 4;
        const int j  = r / 19;            // e0 / 76, exact since 76 = 4*19
        const int i0 = e0 - j * WW;

        v4f px = __builtin_nontemporal_load((const v4f*)(base + e0));
        v4f py = __builtin_nontemporal_load((const v4f*)(base + HWSZ + e0));
        v4f pw = __builtin_nontemporal_load((const v4f*)(base + 2 * HWSZ + e0));
        v4f ph = __builtin_nontemporal_load((const v4f*)(base + 3 * HWSZ + e0));
        v4f pc = __builtin_nontemporal_load((const v4f*)(base + 4 * HWSZ + e0));

        const bool rowhit = anchit && (j == gj) && (gi >= i0) && (gi < i0 + 4);

#pragma unroll
        for (int k = 0; k < 4; ++k) {
            float sx = sigmoidf_fast(px[k]);
            float sy = sigmoidf_fast(py[k]);
            float sc = sigmoidf_fast(pc[k]);
            float bw = __expf(pw[k]) * anw;
            float bh = __expf(ph[k]) * anh;
            float bx = sx + (float)(i0 + k);
            float by = sy + (float)j;
            // IoU(gt, pred-box)
            float mx = fminf(gxm, bx - bw * 0.5f);
            float Mx = fmaxf(gxM, bx + bw * 0.5f);
            float my = fminf(gym, by - bh * 0.5f);
            float My = fmaxf(gyM, by + bh * 0.5f);
            float cw = gw + bw - (Mx - mx);
            float ch = gh + bh - (My - my);
            float carea = (cw <= 0.f || ch <= 0.f) ? 0.f : cw * ch;
            float uarea = garea + bw * bh - carea;
            float iou = carea / uarea;

            float cmask = (iou > SIL_THRESH) ? 0.f : 1.f;
            float tx = 0.5f, ty = 0.5f, tw = 0.f, th = 0.f, tconf = 0.f;
            if (rowhit && (i0 + k) == gi) {
                cmask = OBJECT_SCALE;
                tx = tx_s; ty = ty_s; tw = tw_s; th = th_s;
                tconf = iou;   // iou_t == iou_all at the responsible cell
            }
            float dx = sx - tx, dy = sy - ty;
            float dw = pw[k] - tw, dh = ph[k] - th;
            float dc = sc - tconf;
            ax += dx * dx;
            ay += dy * dy;
            aw_ += dw * dw;
            ah_ += dh * dh;
            ac += cmask * dc * dc;
        }
    }

    // block reduction: wave shuffle -> LDS -> 5 atomics per block
    __shared__ float sred[4][5];
    int lane = threadIdx.x & 63;
    int wid  = threadIdx.x >> 6;
    float vals[5] = {ax, ay, aw_, ah_, ac};
#pragma unroll
    for (int v = 0; v < 5; ++v) {
        float x = vals[v];
#pragma unroll
        for (int off = 32; off > 0; off >>= 1) x += __shfl_down(x, off, 64);
        if (lane == 0) sred[wid][v] = x;
    }
    __syncthreads();
    if (threadIdx.x < 5) {
        float s = sred[0][threadIdx.x] + sred[1][threadIdx.x] +
                  sred[2][threadIdx.x] + sred[3][threadIdx.x];
        atomicAdd(&ws[threadIdx.x], s);
    }
}

__global__ void finish_kernel(const float* __restrict__ ws, float* __restrict__ out) {
    float lx = ws[0] * 0.5f;
    float ly = ws[1] * 0.5f;
    float lw = ws[2] * 0.5f;
    float lh = ws[3] * 0.5f;
    float lc = ws[4] * 0.5f;
    out[0] = lx + ly + lw + lh + lc;
    out[1] = lx;
    out[2] = ly;
    out[3] = lw;
    out[4] = lh;
    out[5] = lc;
}

extern "C" void kernel_launch(void* const* d_in, const int* in_sizes, int n_in,
                              void* d_out, int out_size, void* d_ws, size_t ws_size,
                              hipStream_t stream) {
    const float* pred   = (const float*)d_in[0];
    const float* target = (const float*)d_in[1];
    float* ws  = (float*)d_ws;
    float* out = (float*)d_out;
    int bs = in_sizes[1] / 4;   // 512

    prep_kernel<<<1, 512, 0, stream>>>(target, ws, bs);
    region_loss_main<<<bs * NA, 256, 0, stream>>>(pred, ws);
    finish_kernel<<<1, 1, 0, stream>>>(ws, out);
}

// Round 3
// 377.323 us; speedup vs baseline: 1.0754x; 1.0162x over previous
//
#include <hip/hip_runtime.h>
#include <math.h>

#define NA 5
#define HH 76
#define WW 76
#define HWSZ (HH * WW)          // 5776
#define HW4 (HWSZ / 4)          // 1444
#define NBLK (512 * NA)         // 2560 main-kernel blocks
#define OBJECT_SCALE 5.0f
#define SIL_THRESH 0.6f

// ws layout (floats):
//   [REC_OFF + b*REC_STRIDE ...): per-batch records (512 * 12 floats)
//   [PART_OFF + blk*8 ...): per-block partial sums (5 used, 8 stride = 32 B slots)
// record: 0:gx 1:gy 2:gw 3:gh 4:tx 5:ty 6:tw 7:th 8:best(int) 9:gi(int) 10:gj(int) 11:pad
#define REC_OFF 16
#define REC_STRIDE 12
#define PART_OFF 8192

__constant__ float ANC_W[NA] = {0.57273f, 1.87446f, 3.33843f, 7.88282f, 9.77052f};
__constant__ float ANC_H[NA] = {0.677385f, 2.06253f, 5.47434f, 3.52778f, 9.16828f};

typedef float v4f __attribute__((ext_vector_type(4)));

__global__ void prep_kernel(const float* __restrict__ target, float* __restrict__ ws, int bs) {
    int b = threadIdx.x;
    if (b >= bs) return;
    float gx = target[b * 4 + 0] * (float)WW;
    float gy = target[b * 4 + 1] * (float)HH;
    float gw = target[b * 4 + 2] * (float)WW;
    float gh = target[b * 4 + 3] * (float)HH;
    // best anchor: IoU of (0,0,gw,gh) vs (0,0,aw,ah) reduces to aligned-box IoU
    int best = 0;
    float bestv = -1.0f;
#pragma unroll
    for (int a = 0; a < NA; ++a) {
        float aw = ANC_W[a], ah = ANC_H[a];
        float inter = fminf(gw, aw) * fminf(gh, ah);
        float uni = gw * gh + aw * ah - inter;
        float iou = inter / uni;
        if (iou > bestv) { bestv = iou; best = a; }   // first-max wins ties (matches argmax)
    }
    int gi = (int)gx;
    int gj = (int)gy;
    float* r = ws + REC_OFF + b * REC_STRIDE;
    r[0] = gx; r[1] = gy; r[2] = gw; r[3] = gh;
    r[4] = gx - (float)gi;
    r[5] = gy - (float)gj;
    r[6] = logf(gw / ANC_W[best]);
    r[7] = logf(gh / ANC_H[best]);
    ((int*)r)[8] = best;
    ((int*)r)[9] = gi;
    ((int*)r)[10] = gj;
}

__device__ __forceinline__ float sigmoidf_fast(float x) {
    return 1.0f / (1.0f + __expf(-x));
}

// One block per (b, a) plane: grid.x == bs * NA == 2560.
__global__ __launch_bounds__(256) void
region_loss_main(const float* __restrict__ pred, float* __restrict__ ws) {
    const int ba = blockIdx.x;
    const int b  = ba / NA;
    const int a  = ba - b * NA;

    // per-batch record: uniform per block, cached
    const float* rec = ws + REC_OFF + b * REC_STRIDE;
    const float gx = rec[0], gy = rec[1], gw = rec[2], gh = rec[3];
    const float tx_s = rec[4], ty_s = rec[5], tw_s = rec[6], th_s = rec[7];
    const int best = ((const int*)rec)[8];
    const int gi   = ((const int*)rec)[9];
    const int gj   = ((const int*)rec)[10];
    const float anw = ANC_W[a], anh = ANC_H[a];
    const bool anchit = (a == best);
    const float gxm = gx - gw * 0.5f, gxM = gx + gw * 0.5f;
    const float gym = gy - gh * 0.5f, gyM = gy + gh * 0.5f;
    const float garea = gw * gh;

    const float* base = pred + (size_t)ba * 5 * HWSZ;
    float ax = 0.f, ay = 0.f, aw_ = 0.f, ah_ = 0.f, ac = 0.f;

    for (int r = threadIdx.x; r < HW4; r += 256) {
        const int e0 = r * 4;
        const int j  = r / 19;            // e0 / 76, exact since 76 = 4*19
        const int i0 = e0 - j * WW;

        v4f px = __builtin_nontemporal_load((const v4f*)(base + e0));
        v4f py = __builtin_nontemporal_load((const v4f*)(base + HWSZ + e0));
        v4f pw = __builtin_nontemporal_load((const v4f*)(base + 2 * HWSZ + e0));
        v4f ph = __builtin_nontemporal_load((const v4f*)(base + 3 * HWSZ + e0));
        v4f pc = __builtin_nontemporal_load((const v4f*)(base + 4 * HWSZ + e0));

        const bool rowhit = anchit && (j == gj) && (gi >= i0) && (gi < i0 + 4);

#pragma unroll
        for (int k = 0; k < 4; ++k) {
            float sx = sigmoidf_fast(px[k]);
            float sy = sigmoidf_fast(py[k]);
            float sc = sigmoidf_fast(pc[k]);
            float bw = __expf(pw[k]) * anw;
            float bh = __expf(ph[k]) * anh;
            float bx = sx + (float)(i0 + k);
            float by = sy + (float)j;
            // IoU(gt, pred-box)
            float mx = fminf(gxm, bx - bw * 0.5f);
            float Mx = fmaxf(gxM, bx + bw * 0.5f);
            float my = fminf(gym, by - bh * 0.5f);
            float My = fmaxf(gyM, by + bh * 0.5f);
            float cw = gw + bw - (Mx - mx);
            float ch = gh + bh - (My - my);
            float carea = (cw <= 0.f || ch <= 0.f) ? 0.f : cw * ch;
            float uarea = garea + bw * bh - carea;
            float iou = carea / uarea;

            float cmask = (iou > SIL_THRESH) ? 0.f : 1.f;
            float tx = 0.5f, ty = 0.5f, tw = 0.f, th = 0.f, tconf = 0.f;
            if (rowhit && (i0 + k) == gi) {
                cmask = OBJECT_SCALE;
                tx = tx_s; ty = ty_s; tw = tw_s; th = th_s;
                tconf = iou;   // iou_t == iou_all at the responsible cell
            }
            float dx = sx - tx, dy = sy - ty;
            float dw = pw[k] - tw, dh = ph[k] - th;
            float dc = sc - tconf;
            ax += dx * dx;
            ay += dy * dy;
            aw_ += dw * dw;
            ah_ += dh * dh;
            ac += cmask * dc * dc;
        }
    }

    // block reduction: wave shuffle -> LDS -> per-block partial store (NO atomics)
    __shared__ float sred[4][5];
    int lane = threadIdx.x & 63;
    int wid  = threadIdx.x >> 6;
    float vals[5] = {ax, ay, aw_, ah_, ac};
#pragma unroll
    for (int v = 0; v < 5; ++v) {
        float x = vals[v];
#pragma unroll
        for (int off = 32; off > 0; off >>= 1) x += __shfl_down(x, off, 64);
        if (lane == 0) sred[wid][v] = x;
    }
    __syncthreads();
    if (threadIdx.x < 5) {
        float s = sred[0][threadIdx.x] + sred[1][threadIdx.x] +
                  sred[2][threadIdx.x] + sred[3][threadIdx.x];
        ws[PART_OFF + blockIdx.x * 8 + threadIdx.x] = s;
    }
}

// Reduce 2560 x 5 partials and write the 6 outputs.
__global__ __launch_bounds__(256) void
reduce_finish(const float* __restrict__ ws, float* __restrict__ out) {
    float s0 = 0.f, s1 = 0.f, s2 = 0.f, s3 = 0.f, s4 = 0.f;
    for (int i = threadIdx.x; i < NBLK; i += 256) {
        const float* p = ws + PART_OFF + i * 8;
        s0 += p[0]; s1 += p[1]; s2 += p[2]; s3 += p[3]; s4 += p[4];
    }
    __shared__ float sred[4][5];
    int lane = threadIdx.x & 63;
    int wid  = threadIdx.x >> 6;
    float vals[5] = {s0, s1, s2, s3, s4};
#pragma unroll
    for (int v = 0; v < 5; ++v) {
        float x = vals[v];
#pragma unroll
        for (int off = 32; off > 0; off >>= 1) x += __shfl_down(x, off, 64);
        if (lane == 0) sred[wid][v] = x;
    }
    __syncthreads();
    if (threadIdx.x == 0) {
        float lx = (sred[0][0] + sred[1][0] + sred[2][0] + sred[3][0]) * 0.5f;
        float ly = (sred[0][1] + sred[1][1] + sred[2][1] + sred[3][1]) * 0.5f;
        float lw = (sred[0][2] + sred[1][2] + sred[2][2] + sred[3][2]) * 0.5f;
        float lh = (sred[0][3] + sred[1][3] + sred[2][3] + sred[3][3]) * 0.5f;
        float lc = (sred[0][4] + sred[1][4] + sred[2][4] + sred[3][4]) * 0.5f;
        out[0] = lx + ly + lw + lh + lc;
        out[1] = lx;
        out[2] = ly;
        out[3] = lw;
        out[4] = lh;
        out[5] = lc;
    }
}

extern "C" void kernel_launch(void* const* d_in, const int* in_sizes, int n_in,
                              void* d_out, int out_size, void* d_ws, size_t ws_size,
                              hipStream_t stream) {
    const float* pred   = (const float*)d_in[0];
    const float* target = (const float*)d_in[1];
    float* ws  = (float*)d_ws;
    float* out = (float*)d_out;
    int bs = in_sizes[1] / 4;   // 512

    prep_kernel<<<1, 512, 0, stream>>>(target, ws, bs);
    region_loss_main<<<bs * NA, 256, 0, stream>>>(pred, ws);
    reduce_finish<<<1, 256, 0, stream>>>(ws, out);
}